// Round 3
// baseline (13233.585 us; speedup 1.0000x reference)
//
#include <hip/hip_runtime.h>
#include <math.h>

#define NB 8
#define NC 684
#define NH 16
#define NW 64
#define NHW 1024
#define NHID 256
#define NAD 512
#define NV 111
#define NT 36
#define NBLK 256

__device__ __forceinline__ float wred_sum(float v){
  #pragma unroll
  for (int o = 32; o > 0; o >>= 1) v += __shfl_xor(v, o, 64);
  return v;
}
__device__ __forceinline__ float wred_max(float v){
  #pragma unroll
  for (int o = 32; o > 0; o >>= 1) v = fmaxf(v, __shfl_xor(v, o, 64));
  return v;
}

// sharded grid barrier: slot used once per launch; bar[] zeroed via hipMemsetAsync each launch
__device__ __forceinline__ void gbar(unsigned* bar, int slot, int g){
  __syncthreads();
  if (threadIdx.x == 0){
    __threadfence();
    __hip_atomic_fetch_add(bar + slot*8 + (g & 7), 1u, __ATOMIC_RELEASE, __HIP_MEMORY_SCOPE_AGENT);
    for (;;){
      unsigned s = 0;
      #pragma unroll
      for (int i = 0; i < 8; i++)
        s += __hip_atomic_load(bar + slot*8 + i, __ATOMIC_RELAXED, __HIP_MEMORY_SCOPE_AGENT);
      if (s >= NBLK) break;
      __builtin_amdgcn_s_sleep(2);
    }
    __threadfence();
  }
  __syncthreads();
}

// ---------------- P0: dmask, msum, ys/xs, idt, zero alpha_sum
__global__ void k_p0(const float* __restrict__ im, float* __restrict__ dmask,
                     float* __restrict__ msum, float* __restrict__ ys, float* __restrict__ xs,
                     float* __restrict__ idt, float* __restrict__ asum)
{
  const int tid = threadIdx.x; // 256 threads, 1 block
  for (int i = tid; i < NB*NHW; i += 256){
    int b = i >> 10, hw = i & 1023; int h = hw >> 6, w = hw & 63;
    dmask[i] = im[b*(256*1024) + (h*16)*1024 + (w*16)];
    asum[i] = 0.f;
  }
  if (tid < 128) idt[tid] = expf(-(float)tid * (9.210340371976184f/128.f));
  __syncthreads();
  if (tid < 8){
    float s = 0.f;
    for (int i = 0; i < NHW; i++) s += dmask[tid*NHW + i];
    msum[tid] = s;
  }
  for (int p = tid; p < NB*NW; p += 256){
    int b = p >> 6, w = p & 63;
    float tot = 0.f;
    for (int h = 0; h < NH; h++) tot += dmask[b*NHW + h*64 + w];
    float inv = 6.283185307179586f/(tot + 1e-6f);
    float run = 0.f;
    for (int h = 0; h < NH; h++){ run += dmask[b*NHW + h*64 + w]; ys[b*NHW + h*64 + w] = run*inv; }
  }
  for (int p = tid; p < NB*NH; p += 256){
    int b = p >> 4, h = p & 15;
    float tot = 0.f;
    for (int w = 0; w < NW; w++) tot += dmask[b*NHW + h*64 + w];
    float inv = 6.283185307179586f/(tot + 1e-6f);
    float run = 0.f;
    for (int w = 0; w < NW; w++){ run += dmask[b*NHW + h*64 + w]; xs[b*NHW + h*64 + w] = run*inv; }
  }
}

// ---------------- P1: masked average
__global__ void k_avg(const float* __restrict__ cnn, const float* __restrict__ dmask,
                      const float* __restrict__ msum, float* __restrict__ avg)
{
  int gid = blockIdx.x*blockDim.x + threadIdx.x;
  int gw = gid >> 6, lane = gid & 63;
  int nw = (gridDim.x*blockDim.x) >> 6;
  for (int ow = gw; ow < NB*NC; ow += nw){
    int b = ow / NC;
    const float* base = cnn + (size_t)ow * NHW;
    const float* dm = dmask + b*NHW;
    float s = 0.f;
    for (int i = lane; i < NHW; i += 64) s += base[i]*dm[i];
    s = wred_sum(s);
    if (lane == 0) avg[ow] = s / msum[b];
  }
}

// ---------------- P2: hidden0 (into hbuf[1]) + counting_ctx
__global__ void k_init(const float* __restrict__ avg, const float* __restrict__ iW, const float* __restrict__ ib,
                       const float* __restrict__ cp, const float* __restrict__ cW, const float* __restrict__ cb,
                       float* __restrict__ hid, float* __restrict__ cctx)
{
  int gid = blockIdx.x*blockDim.x + threadIdx.x;
  int gw = gid >> 6, lane = gid & 63;
  int nw = (gridDim.x*blockDim.x) >> 6;
  for (int ow = gw; ow < 2*NB*NHID; ow += nw){
    if (ow < NB*NHID){
      int b = ow >> 8, j = ow & 255;
      float s = 0.f;
      for (int k = lane; k < NC; k += 64) s += avg[b*NC + k]*iW[j*NC + k];
      s = wred_sum(s);
      if (lane == 0) hid[ow] = tanhf(s + ib[j]);
    } else {
      int o = ow - NB*NHID; int b = o >> 8, j = o & 255;
      float s = 0.f;
      for (int k = lane; k < NV; k += 64) s += cp[b*NV + k]*cW[j*NV + k];
      s = wred_sum(s);
      if (lane == 0) cctx[o] = s + cb[j];
    }
  }
}

// ---------------- P3: trans GEMM (128x128 tile, 8x8/thread) + bias + sine pos-emb
__global__ __launch_bounds__(256) void k_gemm_trans(const float* __restrict__ cnn, const float* __restrict__ ew,
     const float* __restrict__ eb, const float* __restrict__ ys, const float* __restrict__ xs,
     const float* __restrict__ idt, float* __restrict__ trans)
{
  const int m0 = blockIdx.x << 7;   // 0..8191
  const int n0 = blockIdx.y << 7;   // 0..511
  const int b  = m0 >> 10;
  const int hw0 = m0 & 1023;
  __shared__ float As[16][128];
  __shared__ float Bs[16][132];
  const int tid = threadIdx.x;
  const int tx = tid & 15, ty = tid >> 4;  // tx -> n(d), ty -> m(hw)
  float acc[8][8];
  #pragma unroll
  for (int i=0;i<8;i++)
    #pragma unroll
    for (int j=0;j<8;j++) acc[i][j]=0.f;
  for (int c0 = 0; c0 < NC; c0 += 16){
    #pragma unroll
    for (int u = 0; u < 8; u++){
      int idx = tid + (u<<8);
      int cc = idx >> 7, mm = idx & 127;
      int c = c0 + cc;
      As[cc][mm] = (c < NC) ? cnn[((size_t)b*NC + c)*NHW + hw0 + mm] : 0.f;
    }
    #pragma unroll
    for (int u = 0; u < 8; u++){
      int idx = tid + (u<<8);
      int nn = idx >> 4, cc = idx & 15;
      int c = c0 + cc;
      Bs[cc][nn] = (c < NC) ? ew[(size_t)(n0 + nn)*NC + c] : 0.f;
    }
    __syncthreads();
    #pragma unroll
    for (int k = 0; k < 16; k++){
      float a[8], bb[8];
      #pragma unroll
      for (int i=0;i<8;i++) a[i] = As[k][ty*8+i];
      #pragma unroll
      for (int j=0;j<8;j++) bb[j] = Bs[k][tx*8+j];
      #pragma unroll
      for (int i=0;i<8;i++)
        #pragma unroll
        for (int j=0;j<8;j++) acc[i][j] += a[i]*bb[j];
    }
    __syncthreads();
  }
  float ebv[8], idtv[8]; int codd[8];
  #pragma unroll
  for (int j = 0; j < 8; j++){
    int d = n0 + tx*8 + j;
    ebv[j] = eb[d];
    idtv[j] = (d < 256) ? idt[d>>1] : idt[(d-256)>>1];
    codd[j] = d & 1;
  }
  const int usex = (n0 + tx*8) >= 256;
  #pragma unroll
  for (int i = 0; i < 8; i++){
    int hw = hw0 + ty*8 + i;
    float ysv = ys[(b<<10) + hw], xsv = xs[(b<<10) + hw];
    float base = usex ? xsv : ysv;
    float o[8];
    #pragma unroll
    for (int j = 0; j < 8; j++){
      float arg = base*idtv[j];
      float pe = codd[j] ? cosf(arg) : sinf(arg);
      o[j] = acc[i][j] + ebv[j] + pe;
    }
    float* dst = trans + ((size_t)(b<<10) + hw)*NAD + n0 + tx*8;
    *(float4*)dst = make_float4(o[0],o[1],o[2],o[3]);
    *(float4*)(dst+4) = make_float4(o[4],o[5],o[6],o[7]);
  }
}

// ---------------- P3b: P[b][j][hw] GEMM (128x128 tile, 8x8/thread)
__global__ __launch_bounds__(256) void k_gemm_P(const float* __restrict__ cnn, const float* __restrict__ cxW,
                                               float* __restrict__ P)
{
  const int m0 = blockIdx.x << 7;   // hw
  const int n0 = blockIdx.y << 7;   // j
  const int b  = blockIdx.z;
  __shared__ float As[16][128];
  __shared__ float Bs[16][132];
  const int tid = threadIdx.x;
  const int tx = tid & 15, ty = tid >> 4;  // tx -> m(hw), ty -> n(j)
  float acc[8][8];  // [m][n]
  #pragma unroll
  for (int i=0;i<8;i++)
    #pragma unroll
    for (int j=0;j<8;j++) acc[i][j]=0.f;
  for (int c0 = 0; c0 < NC; c0 += 16){
    #pragma unroll
    for (int u = 0; u < 8; u++){
      int idx = tid + (u<<8);
      int cc = idx >> 7, mm = idx & 127;
      int c = c0 + cc;
      As[cc][mm] = (c < NC) ? cnn[((size_t)b*NC + c)*NHW + m0 + mm] : 0.f;
    }
    #pragma unroll
    for (int u = 0; u < 8; u++){
      int idx = tid + (u<<8);
      int nn = idx >> 4, cc = idx & 15;
      int c = c0 + cc;
      Bs[cc][nn] = (c < NC) ? cxW[(size_t)(n0 + nn)*NC + c] : 0.f;
    }
    __syncthreads();
    #pragma unroll
    for (int k = 0; k < 16; k++){
      float a[8], bb[8];
      #pragma unroll
      for (int i=0;i<8;i++) a[i] = As[k][tx*8+i];
      #pragma unroll
      for (int j=0;j<8;j++) bb[j] = Bs[k][ty*8+j];
      #pragma unroll
      for (int i=0;i<8;i++)
        #pragma unroll
        for (int j=0;j<8;j++) acc[i][j] += a[i]*bb[j];
    }
    __syncthreads();
  }
  #pragma unroll
  for (int j = 0; j < 8; j++){
    int jr = n0 + ty*8 + j;
    float* dst = P + ((size_t)b*NHID + jr)*NHW + m0 + tx*8;
    *(float4*)dst = make_float4(acc[0][j],acc[1][j],acc[2][j],acc[3][j]);
    *(float4*)(dst+4) = make_float4(acc[4][j],acc[5][j],acc[6][j],acc[7][j]);
  }
}

// ---------------- P4: gi + embw for all steps
__global__ void k_pre(const int* __restrict__ labels, const float* __restrict__ emb,
    const float* __restrict__ wih, const float* __restrict__ bih,
    const float* __restrict__ ewW, const float* __restrict__ ewb,
    float* __restrict__ gi, float* __restrict__ embw)
{
  int gid = blockIdx.x*blockDim.x + threadIdx.x;
  int gw = gid >> 6, lane = gid & 63;
  int nw = (gridDim.x*blockDim.x) >> 6;
  const int NGI = NT*NB*768;
  const int NEW_ = NT*NB*256;
  for (int ow = gw; ow < NGI + NEW_; ow += nw){
    if (ow < NGI){
      int i = ow % 768; int tb = ow / 768; int b = tb & 7, t = tb >> 3;
      int word = (t == 0) ? 1 : labels[b*NT + t - 1];
      const float* er = emb + (size_t)word*256;
      float s = 0.f;
      for (int k = lane; k < 256; k += 64) s += er[k]*wih[(size_t)i*256 + k];
      s = wred_sum(s);
      if (lane == 0) gi[ow] = s + bih[i];
    } else {
      int o = ow - NGI; int j = o & 255; int tb = o >> 8; int b = tb & 7, t = tb >> 3;
      int word = (t == 0) ? 1 : labels[b*NT + t - 1];
      const float* er = emb + (size_t)word*256;
      float s = 0.f;
      for (int k = lane; k < 256; k += 64) s += er[k]*ewW[(size_t)j*256 + k];
      s = wred_sum(s);
      if (lane == 0) embw[o] = s + ewb[j];
    }
  }
}

// ---------------- P5: Mt[t][d] = sum_c att_weight_W[d,c]*att_conv_w[c,0,t]
__global__ void k_mt(const float* __restrict__ aw, const float* __restrict__ acw, float* __restrict__ Mt)
{
  __shared__ float col[512];
  int t = blockIdx.x; int tid = threadIdx.x;  // 121 x 256
  for (int c = tid; c < 512; c += 256) col[c] = acw[(size_t)c*121 + t];
  __syncthreads();
  for (int d = tid; d < 512; d += 256){
    float s = 0.f;
    const float4* r4 = (const float4*)(aw + (size_t)d*512);
    for (int k = 0; k < 128; k++){
      float4 w = r4[k];
      s += col[k*4+0]*w.x + col[k*4+1]*w.y + col[k*4+2]*w.z + col[k*4+3]*w.w;
    }
    Mt[t*512 + d] = s;
  }
}

// ---------------- P6: weight transposes for coalesced per-step GEMVs
__global__ void k_tr(const float* __restrict__ whh, const float* __restrict__ ahW,
                     const float* __restrict__ sW, const float* __restrict__ oW,
                     float* __restrict__ whhT, float* __restrict__ ahWT,
                     float* __restrict__ sWT, float* __restrict__ oWT)
{
  int i = blockIdx.x*256 + threadIdx.x;
  int stride = gridDim.x*256;
  for (int x = i; x < 768*256; x += stride){
    int g = x >> 16, k = (x >> 8) & 255, j = x & 255;
    whhT[x] = whh[(size_t)((g<<8)+j)*256 + k];
  }
  for (int x = i; x < 256*512; x += stride){
    int k = x >> 9, d = x & 511;
    ahWT[x] = ahW[(size_t)(d<<8) + k];
  }
  for (int x = i; x < 256*256; x += stride){
    int k = x >> 8, j = x & 255;
    sWT[x] = sW[(size_t)(j<<8) + k];
  }
  for (int x = i; x < 256*NV; x += stride){
    int k = x / NV, v = x - k*NV;
    oWT[x] = oW[(size_t)v*256 + k];
  }
}

// ---------------- persistent step-loop kernel: 256 blocks x 512 threads (1 block/CU)
__global__ __launch_bounds__(512) void k_loop(
  const float* __restrict__ trans, const float* __restrict__ Mt,
  const float* __restrict__ gi, const float* __restrict__ embw,
  const float* __restrict__ whhT, const float* __restrict__ bhh,
  const float* __restrict__ ahWT, const float* __restrict__ ahb,
  const float* __restrict__ acvW, const float* __restrict__ acvb,
  const float* __restrict__ dmask, const float* __restrict__ P,
  const float* __restrict__ sWT, const float* __restrict__ sb,
  const float* __restrict__ cxb, const float* __restrict__ cctx,
  const float* __restrict__ oWT, const float* __restrict__ ob,
  float* __restrict__ hbuf, float* __restrict__ query_g,
  float* __restrict__ energy_g, float* __restrict__ asum_g,
  float* __restrict__ out, unsigned* __restrict__ bar)
{
  const int g = blockIdx.x, tid = threadIdx.x;
  const int b = g >> 5, seg = g & 31;
  const int h = seg >> 1, w0 = (seg & 1) << 5;
  const int lane = tid & 63, wid = tid >> 6;
  const bool isS = (seg == b);
  const bool isA = (seg == b + 8);

  __shared__ float as[11][42];
  __shared__ float part[32][8];
  __shared__ float sm[1024];
  __shared__ float red[20];
  __shared__ float hprev[256], hcurs[256], osb[256], ctxs[256];

  const float wav = acvW[tid];
  const float acb0 = acvb[0];
  const float* tr = trans + ((size_t)((b<<10) + (h<<6) + w0))*NAD + tid;

  // Mt column for this thread's d, held in registers (static indexing only)
  float mtc[121];
  #pragma unroll
  for (int i = 0; i < 121; i++) mtc[i] = Mt[i*512 + tid];

  auto do_A = [&](int t){
    const float* hsrc = hbuf + (((t+1)&1)<<11) + (b<<8);
    if (tid < 256) hprev[tid] = hsrc[tid];
    __syncthreads();
    if (tid < 256){
      const int j = tid;
      float sr=0.f, sz=0.f, sn=0.f;
      #pragma unroll 4
      for (int k = 0; k < 256; k++){
        float hv = hprev[k];
        sr += hv * whhT[(k<<8) + j];
        sz += hv * whhT[((256+k)<<8) + j];
        sn += hv * whhT[((512+k)<<8) + j];
      }
      const float* gg = gi + (size_t)((t<<3) + b)*768;
      float r = 1.f/(1.f + expf(-(gg[j] + sr + bhh[j])));
      float z = 1.f/(1.f + expf(-(gg[j+256] + sz + bhh[j+256])));
      float n = tanhf(gg[j+512] + r*(sn + bhh[j+512]));
      float hv = (1.f - z)*n + z*hprev[j];
      hcurs[j] = hv;
      hbuf[((t&1)<<11) + (b<<8) + j] = hv;
    }
    __syncthreads();
    {
      const int d = tid;
      float s = 0.f;
      #pragma unroll 4
      for (int k = 0; k < 256; k++) s += hcurs[k] * ahWT[(k<<9) + d];
      query_g[(b<<9) + d] = s + ahb[d];
    }
  };

  auto do_S = [&](int t){
    float e0 = energy_g[(b<<10) + tid];
    float e1 = energy_g[(b<<10) + 512 + tid];
    float m = wred_max(fmaxf(e0, e1));
    if (lane == 0) red[wid] = m;
    __syncthreads();
    if (tid == 0){
      float gm = red[0];
      #pragma unroll
      for (int i = 1; i < 8; i++) gm = fmaxf(gm, red[i]);
      red[16] = gm;
    }
    __syncthreads();
    float gm = red[16];
    float x0 = expf(e0 - gm)*dmask[(b<<10) + tid];
    float x1 = expf(e1 - gm)*dmask[(b<<10) + 512 + tid];
    float s = wred_sum(x0 + x1);
    if (lane == 0) red[wid] = s;
    __syncthreads();
    if (tid == 0){
      float ss = 0.f;
      #pragma unroll
      for (int i = 0; i < 8; i++) ss += red[i];
      red[17] = ss;
    }
    __syncthreads();
    float inv = 1.f/(red[17] + 1e-10f);
    float a0 = x0*inv, a1 = x1*inv;
    sm[tid] = a0; sm[512 + tid] = a1;
    asum_g[(b<<10) + tid] += a0;
    asum_g[(b<<10) + 512 + tid] += a1;
    __syncthreads();
    #pragma unroll 1
    for (int jj = 0; jj < 32; jj++){
      int j = (wid<<5) + jj;
      const float* Pr = P + ((size_t)(b<<8) + j)*NHW;
      float acc = 0.f;
      #pragma unroll
      for (int i = 0; i < 16; i++) acc += sm[lane + (i<<6)]*Pr[lane + (i<<6)];
      acc = wred_sum(acc);
      if (lane == 0) ctxs[j] = acc;
    }
    if (tid < 256) hprev[tid] = hbuf[((t&1)<<11) + (b<<8) + tid];
    __syncthreads();
    if (tid < 256){
      const int j = tid;
      float s2 = sb[j] + cxb[j] + embw[(size_t)((t<<3)+b)*256 + j] + cctx[(b<<8)+j] + ctxs[j];
      #pragma unroll 4
      for (int k = 0; k < 256; k++) s2 += hprev[k]*sWT[(k<<8) + j];
      osb[j] = s2;
    }
    __syncthreads();
    if (tid < NV){
      float p = ob[tid];
      #pragma unroll 4
      for (int k = 0; k < 256; k++) p += osb[k]*oWT[k*NV + tid];
      out[(size_t)(b*NT + t)*NV + tid] = p;
    }
  };

  // ---- initial GRU+query for t=0
  if (isA) do_A(0);
  gbar(bar, 0, g);

  #pragma unroll 1
  for (int t = 0; t < NT; t++){
    // ---- E(t): coverage stencil + tanh + energy dot for this block's 32 positions
    for (int idx = tid; idx < 462; idx += 512){
      int r = idx / 42, c = idx - r*42;
      int hi = h + r - 5, wi = w0 + c - 5;
      float v = 0.f;
      if (hi >= 0 && hi < 16 && wi >= 0 && wi < 64) v = asum_g[(b<<10) + (hi<<6) + wi];
      as[r][c] = v;
    }
    __syncthreads();
    {
      const float q = query_g[(b<<9) + tid];
      float acc[32];
      #pragma unroll
      for (int w = 0; w < 32; w++) acc[w] = 0.f;
      #pragma unroll
      for (int ki = 0; ki < 11; ki++){
        float row[42];
        #pragma unroll
        for (int jx = 0; jx < 42; jx++) row[jx] = as[ki][jx];
        float mx = 0.f;
        #pragma unroll
        for (int jx = 0; jx < 42; jx++) mx = fmaxf(mx, fabsf(row[jx]));
        if (mx != 0.f){
          #pragma unroll
          for (int kj = 0; kj < 11; kj++){
            float mv = mtc[ki*11 + kj];
            #pragma unroll
            for (int w = 0; w < 32; w++) acc[w] += row[kj + w]*mv;
          }
        }
      }
      #pragma unroll 1
      for (int w = 0; w < 32; w++){
        float v = wav * tanhf(q + tr[(size_t)w*NAD] + acc[w]);
        v = wred_sum(v);
        if (lane == 0) part[w][wid] = v;
      }
      __syncthreads();
      if (tid < 32){
        float s = acb0;
        #pragma unroll
        for (int i = 0; i < 8; i++) s += part[tid][i];
        energy_g[(b<<10) + (h<<6) + w0 + tid] = s;
      }
    }
    gbar(bar, 1 + 2*t, g);
    if (isS) do_S(t);
    else if (isA && t < NT-1) do_A(t+1);
    gbar(bar, 2 + 2*t, g);
  }
}

extern "C" void kernel_launch(void* const* d_in, const int* in_sizes, int n_in,
                              void* d_out, int out_size, void* d_ws, size_t ws_size,
                              hipStream_t stream)
{
  const float* cnn  = (const float*)d_in[0];
  const float* cp   = (const float*)d_in[1];
  const float* im   = (const float*)d_in[2];
  const float* iW   = (const float*)d_in[3];
  const float* ib   = (const float*)d_in[4];
  const float* emb  = (const float*)d_in[5];
  const float* wih  = (const float*)d_in[6];
  const float* whh  = (const float*)d_in[7];
  const float* bih  = (const float*)d_in[8];
  const float* bhh  = (const float*)d_in[9];
  const float* ahW  = (const float*)d_in[10];
  const float* ahb  = (const float*)d_in[11];
  const float* acw  = (const float*)d_in[12];
  const float* awW  = (const float*)d_in[13];
  const float* acvW = (const float*)d_in[14];
  const float* acvb = (const float*)d_in[15];
  const float* ecw  = (const float*)d_in[16];
  const float* ecb  = (const float*)d_in[17];
  const float* sW   = (const float*)d_in[18];
  const float* sb   = (const float*)d_in[19];
  const float* ewW  = (const float*)d_in[20];
  const float* ewb  = (const float*)d_in[21];
  const float* cxW  = (const float*)d_in[22];
  const float* cxb  = (const float*)d_in[23];
  const float* cW   = (const float*)d_in[24];
  const float* cb   = (const float*)d_in[25];
  const float* oW   = (const float*)d_in[26];
  const float* ob   = (const float*)d_in[27];
  const int*   lab  = (const int*)d_in[28];
  float* out = (float*)d_out;
  float* ws = (float*)d_ws;

  float* dmask  = ws + 0;        // 8192
  float* ys     = ws + 8192;     // 8192
  float* xs     = ws + 16384;    // 8192
  float* idt    = ws + 24576;    // 128
  float* msum   = ws + 24704;    // 16
  float* avg    = ws + 24720;    // 5472
  float* cctx   = ws + 30192;    // 2048
  float* hbuf   = ws + 32240;    // 4096 (2 x 8 x 256)
  float* query  = ws + 36336;    // 4096
  float* asum   = ws + 40432;    // 8192
  float* energy = ws + 48624;    // 8192
  float* gi     = ws + 56816;    // 221184
  float* embw   = ws + 278000;   // 73728
  float* Mt     = ws + 351728;   // 61952
  float* whhT   = ws + 413680;   // 196608
  float* ahWT   = ws + 610288;   // 131072
  float* sWT    = ws + 741360;   // 65536
  float* oWT    = ws + 806896;   // 28416
  unsigned* bar = (unsigned*)(ws + 835312); // 768 words
  float* trans  = ws + 836080;   // 4194304
  float* P      = ws + 5030384;  // 2097152   (total ~28.5 MB)

  hipMemsetAsync((void*)bar, 0, 768*sizeof(unsigned), stream);

  k_p0<<<1, 256, 0, stream>>>(im, dmask, msum, ys, xs, idt, asum);
  k_avg<<<456, 256, 0, stream>>>(cnn, dmask, msum, avg);
  k_init<<<256, 256, 0, stream>>>(avg, iW, ib, cp, cW, cb, hbuf + 2048, cctx);
  k_gemm_trans<<<dim3(64, 4), 256, 0, stream>>>(cnn, ecw, ecb, ys, xs, idt, trans);
  k_gemm_P<<<dim3(8, 2, 8), 256, 0, stream>>>(cnn, cxW, P);
  k_pre<<<1024, 256, 0, stream>>>(lab, emb, wih, bih, ewW, ewb, gi, embw);
  k_mt<<<121, 256, 0, stream>>>(awW, acw, Mt);
  k_tr<<<128, 256, 0, stream>>>(whh, ahW, sW, oW, whhT, ahWT, sWT, oWT);

  k_loop<<<NBLK, 512, 0, stream>>>(trans, Mt, gi, embw, whhT, bhh, ahWT, ahb,
                                   acvW, acvb, dmask, P, sWT, sb, cxb, cctx,
                                   oWT, ob, hbuf, query, energy, asum, out, bar);
}

// Round 4
// 2373.118 us; speedup vs baseline: 5.5765x; 5.5765x over previous
//
#include <hip/hip_runtime.h>
#include <math.h>

#define NB 8
#define NC 684
#define NH 16
#define NW 64
#define NHW 1024
#define NHID 256
#define NAD 512
#define NV 111
#define NT 36

__device__ __forceinline__ float wred_sum(float v){
  #pragma unroll
  for (int o = 32; o > 0; o >>= 1) v += __shfl_xor(v, o, 64);
  return v;
}
__device__ __forceinline__ float wred_max(float v){
  #pragma unroll
  for (int o = 32; o > 0; o >>= 1) v = fmaxf(v, __shfl_xor(v, o, 64));
  return v;
}

// ---------------- P0: dmask, msum, ys/xs, idt, zero alpha_sum
__global__ void k_p0(const float* __restrict__ im, float* __restrict__ dmask,
                     float* __restrict__ msum, float* __restrict__ ys, float* __restrict__ xs,
                     float* __restrict__ idt, float* __restrict__ asum)
{
  const int tid = threadIdx.x; // 256 threads, 1 block
  for (int i = tid; i < NB*NHW; i += 256){
    int b = i >> 10, hw = i & 1023; int h = hw >> 6, w = hw & 63;
    dmask[i] = im[b*(256*1024) + (h*16)*1024 + (w*16)];
    asum[i] = 0.f;
  }
  if (tid < 128) idt[tid] = expf(-(float)tid * (9.210340371976184f/128.f));
  __syncthreads();
  if (tid < 8){
    float s = 0.f;
    for (int i = 0; i < NHW; i++) s += dmask[tid*NHW + i];
    msum[tid] = s;
  }
  for (int p = tid; p < NB*NW; p += 256){
    int b = p >> 6, w = p & 63;
    float tot = 0.f;
    for (int h = 0; h < NH; h++) tot += dmask[b*NHW + h*64 + w];
    float inv = 6.283185307179586f/(tot + 1e-6f);
    float run = 0.f;
    for (int h = 0; h < NH; h++){ run += dmask[b*NHW + h*64 + w]; ys[b*NHW + h*64 + w] = run*inv; }
  }
  for (int p = tid; p < NB*NH; p += 256){
    int b = p >> 4, h = p & 15;
    float tot = 0.f;
    for (int w = 0; w < NW; w++) tot += dmask[b*NHW + h*64 + w];
    float inv = 6.283185307179586f/(tot + 1e-6f);
    float run = 0.f;
    for (int w = 0; w < NW; w++){ run += dmask[b*NHW + h*64 + w]; xs[b*NHW + h*64 + w] = run*inv; }
  }
}

// ---------------- P1: masked average
__global__ void k_avg(const float* __restrict__ cnn, const float* __restrict__ dmask,
                      const float* __restrict__ msum, float* __restrict__ avg)
{
  int gid = blockIdx.x*blockDim.x + threadIdx.x;
  int gw = gid >> 6, lane = gid & 63;
  int nw = (gridDim.x*blockDim.x) >> 6;
  for (int ow = gw; ow < NB*NC; ow += nw){
    int b = ow / NC;
    const float* base = cnn + (size_t)ow * NHW;
    const float* dm = dmask + b*NHW;
    float s = 0.f;
    for (int i = lane; i < NHW; i += 64) s += base[i]*dm[i];
    s = wred_sum(s);
    if (lane == 0) avg[ow] = s / msum[b];
  }
}

// ---------------- P2: hidden0 (into hbuf[1]) + counting_ctx
__global__ void k_init(const float* __restrict__ avg, const float* __restrict__ iW, const float* __restrict__ ib,
                       const float* __restrict__ cp, const float* __restrict__ cW, const float* __restrict__ cb,
                       float* __restrict__ hid, float* __restrict__ cctx)
{
  int gid = blockIdx.x*blockDim.x + threadIdx.x;
  int gw = gid >> 6, lane = gid & 63;
  int nw = (gridDim.x*blockDim.x) >> 6;
  for (int ow = gw; ow < 2*NB*NHID; ow += nw){
    if (ow < NB*NHID){
      int b = ow >> 8, j = ow & 255;
      float s = 0.f;
      for (int k = lane; k < NC; k += 64) s += avg[b*NC + k]*iW[j*NC + k];
      s = wred_sum(s);
      if (lane == 0) hid[ow] = tanhf(s + ib[j]);
    } else {
      int o = ow - NB*NHID; int b = o >> 8, j = o & 255;
      float s = 0.f;
      for (int k = lane; k < NV; k += 64) s += cp[b*NV + k]*cW[j*NV + k];
      s = wred_sum(s);
      if (lane == 0) cctx[o] = s + cb[j];
    }
  }
}

// ---------------- P3: trans GEMM (128x128 tile, 8x8/thread) + bias + sine pos-emb
__global__ __launch_bounds__(256) void k_gemm_trans(const float* __restrict__ cnn, const float* __restrict__ ew,
     const float* __restrict__ eb, const float* __restrict__ ys, const float* __restrict__ xs,
     const float* __restrict__ idt, float* __restrict__ trans)
{
  const int m0 = blockIdx.x << 7;
  const int n0 = blockIdx.y << 7;
  const int b  = m0 >> 10;
  const int hw0 = m0 & 1023;
  __shared__ float As[16][128];
  __shared__ float Bs[16][132];
  const int tid = threadIdx.x;
  const int tx = tid & 15, ty = tid >> 4;  // tx -> n(d), ty -> m(hw)
  float acc[8][8];
  #pragma unroll
  for (int i=0;i<8;i++)
    #pragma unroll
    for (int j=0;j<8;j++) acc[i][j]=0.f;
  for (int c0 = 0; c0 < NC; c0 += 16){
    #pragma unroll
    for (int u = 0; u < 8; u++){
      int idx = tid + (u<<8);
      int cc = idx >> 7, mm = idx & 127;
      int c = c0 + cc;
      As[cc][mm] = (c < NC) ? cnn[((size_t)b*NC + c)*NHW + hw0 + mm] : 0.f;
    }
    #pragma unroll
    for (int u = 0; u < 8; u++){
      int idx = tid + (u<<8);
      int nn = idx >> 4, cc = idx & 15;
      int c = c0 + cc;
      Bs[cc][nn] = (c < NC) ? ew[(size_t)(n0 + nn)*NC + c] : 0.f;
    }
    __syncthreads();
    #pragma unroll
    for (int k = 0; k < 16; k++){
      float a[8], bb[8];
      #pragma unroll
      for (int i=0;i<8;i++) a[i] = As[k][ty*8+i];
      #pragma unroll
      for (int j=0;j<8;j++) bb[j] = Bs[k][tx*8+j];
      #pragma unroll
      for (int i=0;i<8;i++)
        #pragma unroll
        for (int j=0;j<8;j++) acc[i][j] += a[i]*bb[j];
    }
    __syncthreads();
  }
  float ebv[8], idtv[8]; int codd[8];
  #pragma unroll
  for (int j = 0; j < 8; j++){
    int d = n0 + tx*8 + j;
    ebv[j] = eb[d];
    idtv[j] = (d < 256) ? idt[d>>1] : idt[(d-256)>>1];
    codd[j] = d & 1;
  }
  const int usex = (n0 + tx*8) >= 256;
  #pragma unroll
  for (int i = 0; i < 8; i++){
    int hw = hw0 + ty*8 + i;
    float ysv = ys[(b<<10) + hw], xsv = xs[(b<<10) + hw];
    float base = usex ? xsv : ysv;
    float o[8];
    #pragma unroll
    for (int j = 0; j < 8; j++){
      float arg = base*idtv[j];
      float pe = codd[j] ? cosf(arg) : sinf(arg);
      o[j] = acc[i][j] + ebv[j] + pe;
    }
    float* dst = trans + ((size_t)(b<<10) + hw)*NAD + n0 + tx*8;
    *(float4*)dst = make_float4(o[0],o[1],o[2],o[3]);
    *(float4*)(dst+4) = make_float4(o[4],o[5],o[6],o[7]);
  }
}

// ---------------- P4: gi + embw for all steps
__global__ void k_pre(const int* __restrict__ labels, const float* __restrict__ emb,
    const float* __restrict__ wih, const float* __restrict__ bih,
    const float* __restrict__ ewW, const float* __restrict__ ewb,
    float* __restrict__ gi, float* __restrict__ embw)
{
  int gid = blockIdx.x*blockDim.x + threadIdx.x;
  int gw = gid >> 6, lane = gid & 63;
  int nw = (gridDim.x*blockDim.x) >> 6;
  const int NGI = NT*NB*768;
  const int NEW_ = NT*NB*256;
  for (int ow = gw; ow < NGI + NEW_; ow += nw){
    if (ow < NGI){
      int i = ow % 768; int tb = ow / 768; int b = tb & 7, t = tb >> 3;
      int word = (t == 0) ? 1 : labels[b*NT + t - 1];
      const float* er = emb + (size_t)word*256;
      float s = 0.f;
      for (int k = lane; k < 256; k += 64) s += er[k]*wih[(size_t)i*256 + k];
      s = wred_sum(s);
      if (lane == 0) gi[ow] = s + bih[i];
    } else {
      int o = ow - NGI; int j = o & 255; int tb = o >> 8; int b = tb & 7, t = tb >> 3;
      int word = (t == 0) ? 1 : labels[b*NT + t - 1];
      const float* er = emb + (size_t)word*256;
      float s = 0.f;
      for (int k = lane; k < 256; k += 64) s += er[k]*ewW[(size_t)j*256 + k];
      s = wred_sum(s);
      if (lane == 0) embw[o] = s + ewb[j];
    }
  }
}

// ---------------- P5: Mt[tap][d] = sum_c att_weight_W[d,c]*att_conv_w[c,0,tap]
__global__ void k_mt(const float* __restrict__ aw, const float* __restrict__ acw, float* __restrict__ Mt)
{
  __shared__ float col[512];
  int t = blockIdx.x; int tid = threadIdx.x;  // 121 x 256
  for (int c = tid; c < 512; c += 256) col[c] = acw[(size_t)c*121 + t];
  __syncthreads();
  for (int d = tid; d < 512; d += 256){
    float s = 0.f;
    const float4* r4 = (const float4*)(aw + (size_t)d*512);
    for (int k = 0; k < 128; k++){
      float4 w = r4[k];
      s += col[k*4+0]*w.x + col[k*4+1]*w.y + col[k*4+2]*w.z + col[k*4+3]*w.w;
    }
    Mt[t*512 + d] = s;
  }
}

// ---------------- P6: SO[v][k] = sum_j oW[v,j]*sW[j,k];  CB[b][v] = ob[v] + sum_j (sb+cxb+cctx[b])[j]*oW[v,j]
__global__ __launch_bounds__(256) void k_so(const float* __restrict__ sW, const float* __restrict__ oW,
    const float* __restrict__ sb, const float* __restrict__ cxb, const float* __restrict__ cctx,
    const float* __restrict__ ob, float* __restrict__ SO, float* __restrict__ CB)
{
  const int v = blockIdx.x; const int tid = threadIdx.x;
  float acc = 0.f;
  for (int j = 0; j < 256; j++) acc += sW[(size_t)j*256 + tid] * oW[(size_t)v*256 + j];
  SO[(size_t)v*256 + tid] = acc;
  if (tid < 8){
    float s = ob[v];
    for (int j = 0; j < 256; j++) s += (sb[j] + cxb[j] + cctx[tid*256 + j]) * oW[(size_t)v*256 + j];
    CB[tid*NV + v] = s;
  }
}

// ---------------- P7: embwO[t*8+b][v] = sum_j embw[t*8+b][j]*oW[v,j]
__global__ __launch_bounds__(512) void k_embwO(const float* __restrict__ embw, const float* __restrict__ oW,
                                               float* __restrict__ embwO)
{
  const int v = blockIdx.x; const int tid = threadIdx.x;
  const int lane = tid & 63, wid = tid >> 6;
  __shared__ float ows[256];
  if (tid < 256) ows[tid] = oW[(size_t)v*256 + tid];
  __syncthreads();
  for (int tb = wid; tb < NT*NB; tb += 8){
    float acc = 0.f;
    #pragma unroll
    for (int u = 0; u < 4; u++){ int j = lane + (u<<6); acc += embw[(size_t)tb*256 + j]*ows[j]; }
    acc = wred_sum(acc);
    if (lane == 0) embwO[tb*NV + v] = acc;
  }
}

// ---------------- P8: CO[c][v] = sum_j cxW[j,c]*oW[v,j]  (padded to [c][128], pad=0)
__global__ __launch_bounds__(256) void k_co(const float* __restrict__ cxW, const float* __restrict__ oW,
                                            float* __restrict__ CO)
{
  const int c = blockIdx.x*256 + threadIdx.x;
  const int v = blockIdx.y;
  if (c >= NC) return;
  float acc = 0.f;
  for (int j = 0; j < 256; j++) acc += cxW[(size_t)j*NC + c] * oW[(size_t)v*256 + j];
  CO[(size_t)c*128 + v] = acc;
  if (v == 0){
    for (int vv = NV; vv < 128; vv++) CO[(size_t)c*128 + vv] = 0.f;
  }
}

// ---------------- P9: PO[b][v][hw] = sum_c cnn[b,c,hw]*CO[c][v]   (128x128 tile GEMM)
__global__ __launch_bounds__(256) void k_gemm_PO(const float* __restrict__ cnn, const float* __restrict__ CO,
                                                 float* __restrict__ PO)
{
  const int m0 = blockIdx.x << 7;   // hw
  const int b  = blockIdx.z;
  __shared__ float As[16][128];
  __shared__ float Bs[16][132];
  const int tid = threadIdx.x;
  const int tx = tid & 15, ty = tid >> 4;  // tx -> hw, ty -> v
  float acc[8][8];
  #pragma unroll
  for (int i=0;i<8;i++)
    #pragma unroll
    for (int j=0;j<8;j++) acc[i][j]=0.f;
  for (int c0 = 0; c0 < NC; c0 += 16){
    #pragma unroll
    for (int u = 0; u < 8; u++){
      int idx = tid + (u<<8);
      int cc = idx >> 7, mm = idx & 127;
      int c = c0 + cc;
      As[cc][mm] = (c < NC) ? cnn[((size_t)b*NC + c)*NHW + m0 + mm] : 0.f;
    }
    #pragma unroll
    for (int u = 0; u < 8; u++){
      int idx = tid + (u<<8);
      int cc = idx >> 7, nn = idx & 127;
      int c = c0 + cc;
      Bs[cc][nn] = (c < NC) ? CO[(size_t)c*128 + nn] : 0.f;
    }
    __syncthreads();
    #pragma unroll
    for (int k = 0; k < 16; k++){
      float a[8], bb[8];
      #pragma unroll
      for (int i=0;i<8;i++) a[i] = As[k][tx*8+i];
      #pragma unroll
      for (int j=0;j<8;j++) bb[j] = Bs[k][ty*8+j];
      #pragma unroll
      for (int i=0;i<8;i++)
        #pragma unroll
        for (int j=0;j<8;j++) acc[i][j] += a[i]*bb[j];
    }
    __syncthreads();
  }
  #pragma unroll
  for (int j = 0; j < 8; j++){
    int v = ty*8 + j;
    float* dst = PO + (((size_t)b*128 + v)<<10) + m0 + tx*8;
    *(float4*)dst = make_float4(acc[0][j],acc[1][j],acc[2][j],acc[3][j]);
    *(float4*)(dst+4) = make_float4(acc[4][j],acc[5][j],acc[6][j],acc[7][j]);
  }
}

// ---------------- gru slice device helper (j-range r*64..+64); reads hs[], writes hbuf[t&1]
__device__ __forceinline__ void gru_slice(const float* __restrict__ hs, const float* __restrict__ whh,
    const float* __restrict__ bhh, const float* __restrict__ gg, float* __restrict__ hdst,
    int r, int wid, int lane)
{
  #pragma unroll 1
  for (int jj = 0; jj < 8; jj++){
    int j = (r<<6) + (wid<<3) + jj;
    float sr = 0.f, sz = 0.f, sn = 0.f;
    #pragma unroll
    for (int u = 0; u < 4; u++){
      int k = lane + (u<<6);
      float hv = hs[k];
      sr += hv * whh[(size_t)j*256 + k];
      sz += hv * whh[(size_t)(j+256)*256 + k];
      sn += hv * whh[(size_t)(j+512)*256 + k];
    }
    sr = wred_sum(sr); sz = wred_sum(sz); sn = wred_sum(sn);
    if (lane == 0){
      float rr = 1.f/(1.f + expf(-(gg[j] + sr + bhh[j])));
      float zz = 1.f/(1.f + expf(-(gg[j+256] + sz + bhh[j+256])));
      float nn = tanhf(gg[j+512] + rr*(sn + bhh[j+512]));
      hdst[j] = (1.f - zz)*nn + zz*hs[j];
    }
  }
}

// ---------------- P10: initial GRU (t=0): h(-1)=hbuf[1] -> h(0)=hbuf[0]
__global__ __launch_bounds__(512) void k_gq0(const float* __restrict__ hbuf1, const float* __restrict__ whh,
    const float* __restrict__ bhh, const float* __restrict__ gi, float* __restrict__ hbuf0)
{
  const int r = blockIdx.x, b = blockIdx.y;
  const int tid = threadIdx.x, lane = tid & 63, wid = tid >> 6;
  __shared__ float hs[256];
  if (tid < 256) hs[tid] = hbuf1[(b<<8) + tid];
  __syncthreads();
  gru_slice(hs, whh, bhh, gi + (size_t)b*768, hbuf0 + (b<<8), r, wid, lane);
}

// ---------------- per-step: query(tq) = h(tq) @ ahW.T + ahb
__global__ __launch_bounds__(512) void k_query(const float* __restrict__ hbuf, const float* __restrict__ ahW,
    const float* __restrict__ ahb, float* __restrict__ query_g, int tq)
{
  const int b = blockIdx.x >> 3, dc = blockIdx.x & 7;
  const int tid = threadIdx.x, lane = tid & 63, wid = tid >> 6;
  __shared__ float hs[256];
  if (tid < 256) hs[tid] = hbuf[((tq&1)<<11) + (b<<8) + tid];
  __syncthreads();
  #pragma unroll 1
  for (int i = 0; i < 8; i++){
    int d = (dc<<6) + (wid<<3) + i;
    float acc = 0.f;
    #pragma unroll
    for (int u = 0; u < 4; u++){ int k = lane + (u<<6); acc += hs[k]*ahW[(size_t)d*256 + k]; }
    acc = wred_sum(acc);
    if (lane == 0) query_g[(b<<9) + d] = acc + ahb[d];
  }
}

// ---------------- per-step: fused coverage-stencil + tanh + energy reduction
__global__ __launch_bounds__(512) void k_energy(const float* __restrict__ asum, const float* __restrict__ Mt,
     const float* __restrict__ trans, const float* __restrict__ query, const float* __restrict__ acW,
     const float* __restrict__ acb, float* __restrict__ energy)
{
  const int whalf = blockIdx.x, h = blockIdx.y, b = blockIdx.z;
  const int tid = threadIdx.x;  // d = tid, 512 threads
  __shared__ float as[11][76];
  __shared__ float part[32][8];
  for (int idx = tid; idx < 11*74; idx += 512){
    int r = idx / 74, c = idx - r*74;
    int hi = h + r - 5, wi = c - 5;
    float v = 0.f;
    if ((unsigned)hi < 16u && (unsigned)wi < 64u) v = asum[(b<<10) + (hi<<6) + wi];
    as[r][c] = v;
  }
  __syncthreads();
  const int w0 = whalf << 5;
  float acc[32];
  #pragma unroll
  for (int i = 0; i < 32; i++) acc[i] = 0.f;
  #pragma unroll 1
  for (int ki = 0; ki < 11; ki++){
    float row[42];
    #pragma unroll
    for (int j = 0; j < 42; j++) row[j] = as[ki][w0 + j];
    const float* mrow = Mt + ki*11*512 + tid;
    #pragma unroll
    for (int kj = 0; kj < 11; kj++){
      float m = mrow[kj*512];
      #pragma unroll
      for (int w = 0; w < 32; w++) acc[w] += row[kj + w]*m;
    }
  }
  float tv[32];
  const float* tbase = trans + (((size_t)((b<<4) + h) << 6) + w0)*NAD + tid;
  #pragma unroll
  for (int w = 0; w < 32; w++) tv[w] = tbase[(size_t)w*NAD];
  const float q = query[(b<<9) + tid];
  const float wav = acW[tid];
  const int lane = tid & 63, wid = tid >> 6;
  #pragma unroll 1
  for (int w = 0; w < 32; w++){
    float v = wav * tanhf(q + tv[w] + acc[w]);
    v = wred_sum(v);
    if (lane == 0) part[w][wid] = v;
  }
  __syncthreads();
  if (tid < 32){
    float s = acb[0];
    #pragma unroll
    for (int i = 0; i < 8; i++) s += part[tid][i];
    energy[(b<<10) + (h<<6) + w0 + tid] = s;
  }
}

// ---------------- per-step: softmax + asum update + prob finalize + gru(t+1) slice
// grid (4 r, 8 b) x 512
__global__ __launch_bounds__(512) void k_sagpg(const float* __restrict__ energy_g, const float* __restrict__ dmask,
     const float* __restrict__ PO, const float* __restrict__ SO, const float* __restrict__ CB,
     const float* __restrict__ embwO, const float* __restrict__ gi, const float* __restrict__ whh,
     const float* __restrict__ bhh, float* __restrict__ hbuf, float* __restrict__ asum_g,
     float* __restrict__ out, int t)
{
  const int r = blockIdx.x, b = blockIdx.y;
  const int tid = threadIdx.x, lane = tid & 63, wid = tid >> 6;
  __shared__ float al[1024];
  __shared__ float hs[256];
  __shared__ float red[12];
  // softmax (per-batch max; redundant across the 4 r-blocks)
  float e0 = energy_g[(b<<10) + tid];
  float e1 = energy_g[(b<<10) + 512 + tid];
  float m = wred_max(fmaxf(e0, e1));
  if (lane == 0) red[wid] = m;
  if (tid < 256) hs[tid] = hbuf[((t&1)<<11) + (b<<8) + tid];
  __syncthreads();
  if (tid == 0){
    float g = red[0];
    #pragma unroll
    for (int i = 1; i < 8; i++) g = fmaxf(g, red[i]);
    red[8] = g;
  }
  __syncthreads();
  const float g = red[8];
  float x0 = expf(e0 - g)*dmask[(b<<10) + tid];
  float x1 = expf(e1 - g)*dmask[(b<<10) + 512 + tid];
  float s = wred_sum(x0 + x1);
  if (lane == 0) red[wid] = s;
  __syncthreads();
  if (tid == 0){
    float ss = 0.f;
    #pragma unroll
    for (int i = 0; i < 8; i++) ss += red[i];
    red[9] = ss;
  }
  __syncthreads();
  const float inv = 1.f/(red[9] + 1e-10f);
  const float a0 = x0*inv, a1 = x1*inv;
  al[tid] = a0; al[512 + tid] = a1;
  if (r == 0){
    asum_g[(b<<10) + tid] += a0;
    asum_g[(b<<10) + 512 + tid] += a1;
  }
  __syncthreads();
  // prob: v-range [r*28, min(111, r*28+28))
  {
    const int vbase = r*28;
    const int vend = (vbase + 28 < NV) ? vbase + 28 : NV;
    #pragma unroll 1
    for (int v = vbase + wid; v < vend; v += 8){
      const float* POr = PO + (((size_t)b*128 + v) << 10);
      float acc = 0.f;
      #pragma unroll
      for (int i = 0; i < 16; i++){ int hw = lane + (i<<6); acc += al[hw]*POr[hw]; }
      const float* SOr = SO + (size_t)v*256;
      #pragma unroll
      for (int u = 0; u < 4; u++){ int k = lane + (u<<6); acc += hs[k]*SOr[k]; }
      acc = wred_sum(acc);
      if (lane == 0)
        out[((size_t)b*NT + t)*NV + v] = acc + CB[b*NV + v] + embwO[((t<<3)+b)*NV + v];
    }
  }
  // gru(t+1): j-range [r*64, r*64+64)
  if (t < NT-1){
    gru_slice(hs, whh, bhh, gi + (size_t)(((t+1)<<3) + b)*768,
              hbuf + (((t+1)&1)<<11) + (b<<8), r, wid, lane);
  }
}

extern "C" void kernel_launch(void* const* d_in, const int* in_sizes, int n_in,
                              void* d_out, int out_size, void* d_ws, size_t ws_size,
                              hipStream_t stream)
{
  const float* cnn  = (const float*)d_in[0];
  const float* cp   = (const float*)d_in[1];
  const float* im   = (const float*)d_in[2];
  const float* iW   = (const float*)d_in[3];
  const float* ib   = (const float*)d_in[4];
  const float* emb  = (const float*)d_in[5];
  const float* wih  = (const float*)d_in[6];
  const float* whh  = (const float*)d_in[7];
  const float* bih  = (const float*)d_in[8];
  const float* bhh  = (const float*)d_in[9];
  const float* ahW  = (const float*)d_in[10];
  const float* ahb  = (const float*)d_in[11];
  const float* acw  = (const float*)d_in[12];
  const float* awW  = (const float*)d_in[13];
  const float* acvW = (const float*)d_in[14];
  const float* acvb = (const float*)d_in[15];
  const float* ecw  = (const float*)d_in[16];
  const float* ecb  = (const float*)d_in[17];
  const float* sW   = (const float*)d_in[18];
  const float* sb   = (const float*)d_in[19];
  const float* ewW  = (const float*)d_in[20];
  const float* ewb  = (const float*)d_in[21];
  const float* cxW  = (const float*)d_in[22];
  const float* cxb  = (const float*)d_in[23];
  const float* cW   = (const float*)d_in[24];
  const float* cb   = (const float*)d_in[25];
  const float* oW   = (const float*)d_in[26];
  const float* ob   = (const float*)d_in[27];
  const int*   lab  = (const int*)d_in[28];
  float* out = (float*)d_out;
  float* ws = (float*)d_ws;

  float* dmask  = ws + 0;        // 8192
  float* ys     = ws + 8192;     // 8192
  float* xs     = ws + 16384;    // 8192
  float* idt    = ws + 24576;    // 128
  float* msum   = ws + 24704;    // 16
  float* avg    = ws + 24720;    // 5472
  float* cctx   = ws + 30192;    // 2048
  float* hbuf   = ws + 32240;    // 4096 (2 x 8 x 256)
  float* query  = ws + 36336;    // 4096
  float* asum   = ws + 40432;    // 8192
  float* energy = ws + 48624;    // 8192
  float* gi     = ws + 56816;    // 221184
  float* embw   = ws + 278000;   // 73728
  float* Mt     = ws + 351728;   // 61952
  float* SO     = ws + 413680;   // 28416
  float* CB     = ws + 442096;   // 896
  float* embwO  = ws + 442992;   // 32000
  float* CO     = ws + 474992;   // 87552
  float* trans  = ws + 562544;   // 4194304
  float* PO     = ws + 4756848;  // 4194304   (total ~35.8 MB)

  k_p0<<<1, 256, 0, stream>>>(im, dmask, msum, ys, xs, idt, asum);
  k_avg<<<456, 256, 0, stream>>>(cnn, dmask, msum, avg);
  k_init<<<256, 256, 0, stream>>>(avg, iW, ib, cp, cW, cb, hbuf + 2048, cctx);
  k_pre<<<1024, 256, 0, stream>>>(lab, emb, wih, bih, ewW, ewb, gi, embw);
  k_gemm_trans<<<dim3(64, 4), 256, 0, stream>>>(cnn, ecw, ecb, ys, xs, idt, trans);
  k_mt<<<121, 256, 0, stream>>>(awW, acw, Mt);
  k_so<<<NV, 256, 0, stream>>>(sW, oW, sb, cxb, cctx, ob, SO, CB);
  k_embwO<<<NV, 512, 0, stream>>>(embw, oW, embwO);
  k_co<<<dim3(3, NV), 256, 0, stream>>>(cxW, oW, CO);
  k_gemm_PO<<<dim3(8, 1, 8), 256, 0, stream>>>(cnn, CO, PO);
  k_gq0<<<dim3(4, 8), 512, 0, stream>>>(hbuf + 2048, whh, bhh, gi, hbuf);
  k_query<<<64, 512, 0, stream>>>(hbuf, ahW, ahb, query, 0);

  for (int t = 0; t < NT; t++){
    k_energy<<<dim3(2, 16, 8), 512, 0, stream>>>(asum, Mt, trans, query, acvW, acvb, energy);
    k_sagpg<<<dim3(4, 8), 512, 0, stream>>>(energy, dmask, PO, SO, CB, embwO, gi, whh, bhh,
                                            hbuf, asum, out, t);
    if (t < NT-1)
      k_query<<<64, 512, 0, stream>>>(hbuf, ahW, ahb, query, t+1);
  }
}

// Round 5
// 2296.103 us; speedup vs baseline: 5.7635x; 1.0335x over previous
//
#include <hip/hip_runtime.h>
#include <math.h>

#define NB 8
#define NC 684
#define NH 16
#define NW 64
#define NHW 1024
#define NHID 256
#define NAD 512
#define NV 111
#define NT 36

__device__ __forceinline__ float wred_sum(float v){
  #pragma unroll
  for (int o = 32; o > 0; o >>= 1) v += __shfl_xor(v, o, 64);
  return v;
}
__device__ __forceinline__ float wred_max(float v){
  #pragma unroll
  for (int o = 32; o > 0; o >>= 1) v = fmaxf(v, __shfl_xor(v, o, 64));
  return v;
}

// ---------------- P0: dmask, msum, ys/xs, idt, zero alpha_sum
__global__ void k_p0(const float* __restrict__ im, float* __restrict__ dmask,
                     float* __restrict__ msum, float* __restrict__ ys, float* __restrict__ xs,
                     float* __restrict__ idt, float* __restrict__ asum)
{
  const int tid = threadIdx.x; // 256 threads, 1 block
  for (int i = tid; i < NB*NHW; i += 256){
    int b = i >> 10, hw = i & 1023; int h = hw >> 6, w = hw & 63;
    dmask[i] = im[b*(256*1024) + (h*16)*1024 + (w*16)];
    asum[i] = 0.f;
  }
  if (tid < 128) idt[tid] = expf(-(float)tid * (9.210340371976184f/128.f));
  __syncthreads();
  if (tid < 8){
    float s = 0.f;
    for (int i = 0; i < NHW; i++) s += dmask[tid*NHW + i];
    msum[tid] = s;
  }
  for (int p = tid; p < NB*NW; p += 256){
    int b = p >> 6, w = p & 63;
    float tot = 0.f;
    for (int h = 0; h < NH; h++) tot += dmask[b*NHW + h*64 + w];
    float inv = 6.283185307179586f/(tot + 1e-6f);
    float run = 0.f;
    for (int h = 0; h < NH; h++){ run += dmask[b*NHW + h*64 + w]; ys[b*NHW + h*64 + w] = run*inv; }
  }
  for (int p = tid; p < NB*NH; p += 256){
    int b = p >> 4, h = p & 15;
    float tot = 0.f;
    for (int w = 0; w < NW; w++) tot += dmask[b*NHW + h*64 + w];
    float inv = 6.283185307179586f/(tot + 1e-6f);
    float run = 0.f;
    for (int w = 0; w < NW; w++){ run += dmask[b*NHW + h*64 + w]; xs[b*NHW + h*64 + w] = run*inv; }
  }
}

// ---------------- P1: masked average
__global__ void k_avg(const float* __restrict__ cnn, const float* __restrict__ dmask,
                      const float* __restrict__ msum, float* __restrict__ avg)
{
  int gid = blockIdx.x*blockDim.x + threadIdx.x;
  int gw = gid >> 6, lane = gid & 63;
  int nw = (gridDim.x*blockDim.x) >> 6;
  for (int ow = gw; ow < NB*NC; ow += nw){
    int b = ow / NC;
    const float* base = cnn + (size_t)ow * NHW;
    const float* dm = dmask + b*NHW;
    float s = 0.f;
    for (int i = lane; i < NHW; i += 64) s += base[i]*dm[i];
    s = wred_sum(s);
    if (lane == 0) avg[ow] = s / msum[b];
  }
}

// ---------------- P2: hidden0 (into hbuf[1]) + counting_ctx
__global__ void k_init(const float* __restrict__ avg, const float* __restrict__ iW, const float* __restrict__ ib,
                       const float* __restrict__ cp, const float* __restrict__ cW, const float* __restrict__ cb,
                       float* __restrict__ hid, float* __restrict__ cctx)
{
  int gid = blockIdx.x*blockDim.x + threadIdx.x;
  int gw = gid >> 6, lane = gid & 63;
  int nw = (gridDim.x*blockDim.x) >> 6;
  for (int ow = gw; ow < 2*NB*NHID; ow += nw){
    if (ow < NB*NHID){
      int b = ow >> 8, j = ow & 255;
      float s = 0.f;
      for (int k = lane; k < NC; k += 64) s += avg[b*NC + k]*iW[j*NC + k];
      s = wred_sum(s);
      if (lane == 0) hid[ow] = tanhf(s + ib[j]);
    } else {
      int o = ow - NB*NHID; int b = o >> 8, j = o & 255;
      float s = 0.f;
      for (int k = lane; k < NV; k += 64) s += cp[b*NV + k]*cW[j*NV + k];
      s = wred_sum(s);
      if (lane == 0) cctx[o] = s + cb[j];
    }
  }
}

// ---------------- P3: trans GEMM (64x64 tile, 4x4/thread — proven no-spill shape) + pos-emb
__global__ __launch_bounds__(256) void k_trans(const float* __restrict__ cnn, const float* __restrict__ ew,
     const float* __restrict__ eb, const float* __restrict__ ys, const float* __restrict__ xs,
     const float* __restrict__ idt, float* __restrict__ trans)
{
  const int mt = blockIdx.x, nt = blockIdx.y;   // 128 x 8
  const int b = mt >> 4; const int hw0 = (mt & 15) << 6;
  const int n0 = nt << 6;
  __shared__ float As[32][64];
  __shared__ float Bs[32][65];
  const int tid = threadIdx.x;
  const int tx = tid & 15, ty = tid >> 4;
  float acc[4][4];
  #pragma unroll
  for (int i=0;i<4;i++)
    #pragma unroll
    for (int j=0;j<4;j++) acc[i][j]=0.f;
  for (int c0 = 0; c0 < NC; c0 += 32){
    int kc = NC - c0; if (kc > 32) kc = 32;
    for (int idx = tid; idx < 32*64; idx += 256){
      int cc = idx >> 6, mm = idx & 63;
      As[cc][mm] = (cc < kc) ? cnn[((size_t)b*NC + c0 + cc)*NHW + hw0 + mm] : 0.f;
    }
    for (int idx = tid; idx < 32*64; idx += 256){
      int nn = idx >> 5, cc = idx & 31;
      Bs[cc][nn] = (cc < kc) ? ew[(size_t)(n0 + nn)*NC + c0 + cc] : 0.f;
    }
    __syncthreads();
    #pragma unroll
    for (int k = 0; k < 32; k++){
      float a0 = As[k][ty*4+0], a1 = As[k][ty*4+1], a2 = As[k][ty*4+2], a3 = As[k][ty*4+3];
      float b0 = Bs[k][tx*4+0], b1 = Bs[k][tx*4+1], b2 = Bs[k][tx*4+2], b3 = Bs[k][tx*4+3];
      acc[0][0]+=a0*b0; acc[0][1]+=a0*b1; acc[0][2]+=a0*b2; acc[0][3]+=a0*b3;
      acc[1][0]+=a1*b0; acc[1][1]+=a1*b1; acc[1][2]+=a1*b2; acc[1][3]+=a1*b3;
      acc[2][0]+=a2*b0; acc[2][1]+=a2*b1; acc[2][2]+=a2*b2; acc[2][3]+=a2*b3;
      acc[3][0]+=a3*b0; acc[3][1]+=a3*b1; acc[3][2]+=a3*b2; acc[3][3]+=a3*b3;
    }
    __syncthreads();
  }
  #pragma unroll
  for (int i = 0; i < 4; i++){
    int hw = hw0 + ty*4 + i;
    float ysv = ys[(b<<10) + hw], xsv = xs[(b<<10) + hw];
    #pragma unroll
    for (int j = 0; j < 4; j++){
      int d = n0 + tx*4 + j;
      float pe;
      if (d < 256){ int k = d >> 1; float arg = ysv*idt[k]; pe = (d & 1) ? cosf(arg) : sinf(arg); }
      else        { int k = (d-256) >> 1; float arg = xsv*idt[k]; pe = (d & 1) ? cosf(arg) : sinf(arg); }
      trans[(((size_t)(b<<10) + hw) << 9) + d] = acc[i][j] + eb[d] + pe;
    }
  }
}

// ---------------- P4: gi + embw for all steps
__global__ void k_pre(const int* __restrict__ labels, const float* __restrict__ emb,
    const float* __restrict__ wih, const float* __restrict__ bih,
    const float* __restrict__ ewW, const float* __restrict__ ewb,
    float* __restrict__ gi, float* __restrict__ embw)
{
  int gid = blockIdx.x*blockDim.x + threadIdx.x;
  int gw = gid >> 6, lane = gid & 63;
  int nw = (gridDim.x*blockDim.x) >> 6;
  const int NGI = NT*NB*768;
  const int NEW_ = NT*NB*256;
  for (int ow = gw; ow < NGI + NEW_; ow += nw){
    if (ow < NGI){
      int i = ow % 768; int tb = ow / 768; int b = tb & 7, t = tb >> 3;
      int word = (t == 0) ? 1 : labels[b*NT + t - 1];
      const float* er = emb + (size_t)word*256;
      float s = 0.f;
      for (int k = lane; k < 256; k += 64) s += er[k]*wih[(size_t)i*256 + k];
      s = wred_sum(s);
      if (lane == 0) gi[ow] = s + bih[i];
    } else {
      int o = ow - NGI; int j = o & 255; int tb = o >> 8; int b = tb & 7, t = tb >> 3;
      int word = (t == 0) ? 1 : labels[b*NT + t - 1];
      const float* er = emb + (size_t)word*256;
      float s = 0.f;
      for (int k = lane; k < 256; k += 64) s += er[k]*ewW[(size_t)j*256 + k];
      s = wred_sum(s);
      if (lane == 0) embw[o] = s + ewb[j];
    }
  }
}

// ---------------- P5: Mt[tap][d] = sum_c att_weight_W[d,c]*att_conv_w[c,0,tap]
__global__ void k_mt(const float* __restrict__ aw, const float* __restrict__ acw, float* __restrict__ Mt)
{
  __shared__ float col[512];
  int t = blockIdx.x; int tid = threadIdx.x;  // 121 x 256
  for (int c = tid; c < 512; c += 256) col[c] = acw[(size_t)c*121 + t];
  __syncthreads();
  for (int d = tid; d < 512; d += 256){
    float s = 0.f;
    const float4* r4 = (const float4*)(aw + (size_t)d*512);
    for (int k = 0; k < 128; k++){
      float4 w = r4[k];
      s += col[k*4+0]*w.x + col[k*4+1]*w.y + col[k*4+2]*w.z + col[k*4+3]*w.w;
    }
    Mt[t*512 + d] = s;
  }
}

// ---------------- P6: SO = oW@sW; CB[b][v] = ob[v] + (sb+cxb+cctx[b])·oW[v]
__global__ __launch_bounds__(256) void k_so(const float* __restrict__ sW, const float* __restrict__ oW,
    const float* __restrict__ sb, const float* __restrict__ cxb, const float* __restrict__ cctx,
    const float* __restrict__ ob, float* __restrict__ SO, float* __restrict__ CB)
{
  const int v = blockIdx.x; const int tid = threadIdx.x;
  float acc = 0.f;
  for (int j = 0; j < 256; j++) acc += sW[(size_t)j*256 + tid] * oW[(size_t)v*256 + j];
  SO[(size_t)v*256 + tid] = acc;
  if (tid < 8){
    float s = ob[v];
    for (int j = 0; j < 256; j++) s += (sb[j] + cxb[j] + cctx[tid*256 + j]) * oW[(size_t)v*256 + j];
    CB[tid*NV + v] = s;
  }
}

// ---------------- P7: embwO[t*8+b][v] = embw[t*8+b]·oW[v]
__global__ __launch_bounds__(512) void k_embwO(const float* __restrict__ embw, const float* __restrict__ oW,
                                               float* __restrict__ embwO)
{
  const int v = blockIdx.x; const int tid = threadIdx.x;
  const int lane = tid & 63, wid = tid >> 6;
  __shared__ float ows[256];
  if (tid < 256) ows[tid] = oW[(size_t)v*256 + tid];
  __syncthreads();
  for (int tb = wid; tb < NT*NB; tb += 8){
    float acc = 0.f;
    #pragma unroll
    for (int u = 0; u < 4; u++){ int j = lane + (u<<6); acc += embw[(size_t)tb*256 + j]*ows[j]; }
    acc = wred_sum(acc);
    if (lane == 0) embwO[tb*NV + v] = acc;
  }
}

// ---------------- P8: CO[c][v] = sum_j cxW[j,c]*oW[v,j] (padded [c][128])
__global__ __launch_bounds__(256) void k_co(const float* __restrict__ cxW, const float* __restrict__ oW,
                                            float* __restrict__ CO)
{
  const int c = blockIdx.x*256 + threadIdx.x;
  const int v = blockIdx.y;
  if (c >= NC) return;
  float acc = 0.f;
  for (int j = 0; j < 256; j++) acc += cxW[(size_t)j*NC + c] * oW[(size_t)v*256 + j];
  CO[(size_t)c*128 + v] = acc;
  if (v == 0){
    for (int vv = NV; vv < 128; vv++) CO[(size_t)c*128 + vv] = 0.f;
  }
}

// ---------------- P9: PO[b][v][hw] = sum_c cnn[b,c,hw]*CO[c][v] (64x64 tile, 4x4/thread)
__global__ __launch_bounds__(256) void k_gemm_PO(const float* __restrict__ cnn, const float* __restrict__ CO,
                                                 float* __restrict__ PO)
{
  const int m0 = blockIdx.x << 6;   // hw
  const int n0 = blockIdx.y << 6;   // v
  const int b  = blockIdx.z;
  __shared__ float As[32][64];
  __shared__ float Bs[32][65];
  const int tid = threadIdx.x;
  const int tx = tid & 15, ty = tid >> 4;  // tx -> m(hw), ty -> n(v)
  float acc[4][4];  // [m][n]
  #pragma unroll
  for (int i=0;i<4;i++)
    #pragma unroll
    for (int j=0;j<4;j++) acc[i][j]=0.f;
  for (int c0 = 0; c0 < NC; c0 += 32){
    int kc = NC - c0; if (kc > 32) kc = 32;
    for (int idx = tid; idx < 32*64; idx += 256){
      int cc = idx >> 6, mm = idx & 63;
      As[cc][mm] = (cc < kc) ? cnn[((size_t)b*NC + c0 + cc)*NHW + m0 + mm] : 0.f;
    }
    for (int idx = tid; idx < 32*64; idx += 256){
      int cc = idx >> 6, nn = idx & 63;
      Bs[cc][nn] = (cc < kc) ? CO[(size_t)(c0 + cc)*128 + n0 + nn] : 0.f;
    }
    __syncthreads();
    #pragma unroll
    for (int k = 0; k < 32; k++){
      float a0 = As[k][tx*4+0], a1 = As[k][tx*4+1], a2 = As[k][tx*4+2], a3 = As[k][tx*4+3];
      float b0 = Bs[k][ty*4+0], b1 = Bs[k][ty*4+1], b2 = Bs[k][ty*4+2], b3 = Bs[k][ty*4+3];
      acc[0][0]+=a0*b0; acc[0][1]+=a0*b1; acc[0][2]+=a0*b2; acc[0][3]+=a0*b3;
      acc[1][0]+=a1*b0; acc[1][1]+=a1*b1; acc[1][2]+=a1*b2; acc[1][3]+=a1*b3;
      acc[2][0]+=a2*b0; acc[2][1]+=a2*b1; acc[2][2]+=a2*b2; acc[2][3]+=a2*b3;
      acc[3][0]+=a3*b0; acc[3][1]+=a3*b1; acc[3][2]+=a3*b2; acc[3][3]+=a3*b3;
    }
    __syncthreads();
  }
  #pragma unroll
  for (int j = 0; j < 4; j++){
    int v = n0 + ty*4 + j;
    float* dst = PO + (((size_t)b*128 + v)<<10) + m0 + tx*4;
    *(float4*)dst = make_float4(acc[0][j],acc[1][j],acc[2][j],acc[3][j]);
  }
}

// ---------------- gru slice helper (64 j per r)
__device__ __forceinline__ void gru_slice(const float* __restrict__ hs, const float* __restrict__ whh,
    const float* __restrict__ bhh, const float* __restrict__ gg, float* __restrict__ hdst,
    int r, int wid, int lane)
{
  #pragma unroll 1
  for (int jj = 0; jj < 8; jj++){
    int j = (r<<6) + (wid<<3) + jj;
    float sr = 0.f, sz = 0.f, sn = 0.f;
    #pragma unroll
    for (int u = 0; u < 4; u++){
      int k = lane + (u<<6);
      float hv = hs[k];
      sr += hv * whh[(size_t)j*256 + k];
      sz += hv * whh[(size_t)(j+256)*256 + k];
      sn += hv * whh[(size_t)(j+512)*256 + k];
    }
    sr = wred_sum(sr); sz = wred_sum(sz); sn = wred_sum(sn);
    if (lane == 0){
      float rr = 1.f/(1.f + expf(-(gg[j] + sr + bhh[j])));
      float zz = 1.f/(1.f + expf(-(gg[j+256] + sz + bhh[j+256])));
      float nn = tanhf(gg[j+512] + rr*(sn + bhh[j+512]));
      hdst[j] = (1.f - zz)*nn + zz*hs[j];
    }
  }
}

// ---------------- P10: initial GRU (t=0): hbuf[1] -> hbuf[0]
__global__ __launch_bounds__(512) void k_gq0(const float* __restrict__ hbuf1, const float* __restrict__ whh,
    const float* __restrict__ bhh, const float* __restrict__ gi, float* __restrict__ hbuf0)
{
  const int r = blockIdx.x, b = blockIdx.y;
  const int tid = threadIdx.x, lane = tid & 63, wid = tid >> 6;
  __shared__ float hs[256];
  if (tid < 256) hs[tid] = hbuf1[(b<<8) + tid];
  __syncthreads();
  gru_slice(hs, whh, bhh, gi + (size_t)b*768, hbuf0 + (b<<8), r, wid, lane);
}

// ---------------- P11: query(0) into qbuf[0]
__global__ __launch_bounds__(512) void k_query0(const float* __restrict__ hbuf, const float* __restrict__ ahW,
    const float* __restrict__ ahb, float* __restrict__ qbuf)
{
  const int b = blockIdx.x >> 3, dc = blockIdx.x & 7;
  const int tid = threadIdx.x, lane = tid & 63, wid = tid >> 6;
  __shared__ float hs[256];
  if (tid < 256) hs[tid] = hbuf[(b<<8) + tid];
  __syncthreads();
  #pragma unroll 1
  for (int i = 0; i < 8; i++){
    int d = (dc<<6) + (wid<<3) + i;
    float acc = 0.f;
    #pragma unroll
    for (int u = 0; u < 4; u++){ int k = lane + (u<<6); acc += hs[k]*ahW[(size_t)d*256 + k]; }
    acc = wred_sum(acc);
    if (lane == 0) qbuf[(b<<9) + d] = acc + ahb[d];
  }
}

// ---------------- per-step fused: energy(t) on blocks 0..255  ||  gru(t+1)+query(t+1) on blocks 256..263
__global__ __launch_bounds__(512) void k_eg(const float* __restrict__ asum, const float* __restrict__ Mt,
     const float* __restrict__ trans, float* __restrict__ qbuf, const float* __restrict__ acW,
     const float* __restrict__ acb, const float* __restrict__ gi, const float* __restrict__ whhT,
     const float* __restrict__ bhh, const float* __restrict__ ahWT, const float* __restrict__ ahb,
     float* __restrict__ hbuf, float* __restrict__ energy, int t)
{
  const int gid = blockIdx.x;
  const int tid = threadIdx.x;
  __shared__ float as[11][76];
  __shared__ float part[32][8];
  __shared__ float hs[256], hc[256];
  if (gid < 256){
    const int whalf = gid & 1, h = (gid >> 1) & 15, b = gid >> 5;
    for (int idx = tid; idx < 11*74; idx += 512){
      int r = idx / 74, c = idx - r*74;
      int hi = h + r - 5, wi = c - 5;
      float v = 0.f;
      if ((unsigned)hi < 16u && (unsigned)wi < 64u) v = asum[(b<<10) + (hi<<6) + wi];
      as[r][c] = v;
    }
    __syncthreads();
    const int w0 = whalf << 5;
    float acc[32];
    #pragma unroll
    for (int i = 0; i < 32; i++) acc[i] = 0.f;
    #pragma unroll 1
    for (int ki = 0; ki < 11; ki++){
      float row[42];
      #pragma unroll
      for (int j = 0; j < 42; j++) row[j] = as[ki][w0 + j];
      float mx = 0.f;
      #pragma unroll
      for (int j = 0; j < 42; j++) mx = fmaxf(mx, fabsf(row[j]));
      if (mx != 0.f){
        const float* mrow = Mt + ki*11*512 + tid;
        #pragma unroll
        for (int kj = 0; kj < 11; kj++){
          float m = mrow[kj*512];
          #pragma unroll
          for (int w = 0; w < 32; w++) acc[w] += row[kj + w]*m;
        }
      }
    }
    float tv[32];
    const float* tbase = trans + (((size_t)((b<<4) + h) << 6) + w0)*NAD + tid;
    #pragma unroll
    for (int w = 0; w < 32; w++) tv[w] = tbase[(size_t)w*NAD];
    const float q = qbuf[((t&1)<<12) + (b<<9) + tid];
    const float wav = acW[tid];
    const int lane = tid & 63, wid = tid >> 6;
    #pragma unroll 1
    for (int w = 0; w < 32; w++){
      float v = wav * tanhf(q + tv[w] + acc[w]);
      v = wred_sum(v);
      if (lane == 0) part[w][wid] = v;
    }
    __syncthreads();
    if (tid < 32){
      float s = acb[0];
      #pragma unroll
      for (int i = 0; i < 8; i++) s += part[tid][i];
      energy[(b<<10) + (h<<6) + w0 + tid] = s;
    }
  } else {
    if (t + 1 >= NT) return;
    const int b = gid - 256;
    if (tid < 256) hs[tid] = hbuf[((t&1)<<11) + (b<<8) + tid];
    __syncthreads();
    if (tid < 256){
      const int j = tid;
      float sr = 0.f, sz = 0.f, sn = 0.f;
      #pragma unroll 4
      for (int k = 0; k < 256; k++){
        float hv = hs[k];
        sr += hv * whhT[(k<<8) + j];
        sz += hv * whhT[((256+k)<<8) + j];
        sn += hv * whhT[((512+k)<<8) + j];
      }
      const float* gg = gi + (size_t)(((t+1)<<3) + b)*768;
      float r = 1.f/(1.f + expf(-(gg[j] + sr + bhh[j])));
      float z = 1.f/(1.f + expf(-(gg[j+256] + sz + bhh[j+256])));
      float n = tanhf(gg[j+512] + r*(sn + bhh[j+512]));
      float hv = (1.f - z)*n + z*hs[j];
      hc[j] = hv;
      hbuf[(((t+1)&1)<<11) + (b<<8) + j] = hv;
    }
    __syncthreads();
    {
      const int d = tid;
      float s = 0.f;
      #pragma unroll 4
      for (int k = 0; k < 256; k++) s += hc[k]*ahWT[(k<<9) + d];
      qbuf[(((t+1)&1)<<12) + (b<<9) + d] = s + ahb[d];
    }
  }
}

// ---------------- per-step: softmax + asum update + prob finalize; grid (4 r, 8 b) x 512
__global__ __launch_bounds__(512) void k_sap(const float* __restrict__ energy_g, const float* __restrict__ dmask,
     const float* __restrict__ PO, const float* __restrict__ SO, const float* __restrict__ CB,
     const float* __restrict__ embwO, const float* __restrict__ hbuf, float* __restrict__ asum_g,
     float* __restrict__ out, int t)
{
  const int r = blockIdx.x, b = blockIdx.y;
  const int tid = threadIdx.x, lane = tid & 63, wid = tid >> 6;
  __shared__ float al[1024];
  __shared__ float hs[256];
  __shared__ float red[12];
  float e0 = energy_g[(b<<10) + tid];
  float e1 = energy_g[(b<<10) + 512 + tid];
  float m = wred_max(fmaxf(e0, e1));
  if (lane == 0) red[wid] = m;
  if (tid < 256) hs[tid] = hbuf[((t&1)<<11) + (b<<8) + tid];
  __syncthreads();
  if (tid == 0){
    float g = red[0];
    #pragma unroll
    for (int i = 1; i < 8; i++) g = fmaxf(g, red[i]);
    red[8] = g;
  }
  __syncthreads();
  const float g = red[8];
  float x0 = expf(e0 - g)*dmask[(b<<10) + tid];
  float x1 = expf(e1 - g)*dmask[(b<<10) + 512 + tid];
  float s = wred_sum(x0 + x1);
  if (lane == 0) red[wid] = s;
  __syncthreads();
  if (tid == 0){
    float ss = 0.f;
    #pragma unroll
    for (int i = 0; i < 8; i++) ss += red[i];
    red[9] = ss;
  }
  __syncthreads();
  const float inv = 1.f/(red[9] + 1e-10f);
  const float a0 = x0*inv, a1 = x1*inv;
  al[tid] = a0; al[512 + tid] = a1;
  if (r == 0){
    asum_g[(b<<10) + tid] += a0;
    asum_g[(b<<10) + 512 + tid] += a1;
  }
  __syncthreads();
  const int vbase = r*28;
  const int vend = (vbase + 28 < NV) ? vbase + 28 : NV;
  #pragma unroll 1
  for (int v = vbase + wid; v < vend; v += 8){
    const float* POr = PO + (((size_t)b*128 + v) << 10);
    float acc = 0.f;
    #pragma unroll
    for (int i = 0; i < 16; i++){ int hw = lane + (i<<6); acc += al[hw]*POr[hw]; }
    const float* SOr = SO + (size_t)v*256;
    #pragma unroll
    for (int u = 0; u < 4; u++){ int k = lane + (u<<6); acc += hs[k]*SOr[k]; }
    acc = wred_sum(acc);
    if (lane == 0)
      out[((size_t)b*NT + t)*NV + v] = acc + CB[b*NV + v] + embwO[((t<<3)+b)*NV + v];
  }
}

// ---------------- P12: weight transposes (whhT [g][k][j], ahWT [k][d])
__global__ void k_tr(const float* __restrict__ whh, const float* __restrict__ ahW,
                     float* __restrict__ whhT, float* __restrict__ ahWT)
{
  int i = blockIdx.x*256 + threadIdx.x;
  int stride = gridDim.x*256;
  for (int x = i; x < 768*256; x += stride){
    int g = x >> 16, k = (x >> 8) & 255, j = x & 255;
    whhT[x] = whh[(size_t)((g<<8)+j)*256 + k];
  }
  for (int x = i; x < 256*512; x += stride){
    int k = x >> 9, d = x & 511;
    ahWT[x] = ahW[(size_t)(d<<8) + k];
  }
}

extern "C" void kernel_launch(void* const* d_in, const int* in_sizes, int n_in,
                              void* d_out, int out_size, void* d_ws, size_t ws_size,
                              hipStream_t stream)
{
  const float* cnn  = (const float*)d_in[0];
  const float* cp   = (const float*)d_in[1];
  const float* im   = (const float*)d_in[2];
  const float* iW   = (const float*)d_in[3];
  const float* ib   = (const float*)d_in[4];
  const float* emb  = (const float*)d_in[5];
  const float* wih  = (const float*)d_in[6];
  const float* whh  = (const float*)d_in[7];
  const float* bih  = (const float*)d_in[8];
  const float* bhh  = (const float*)d_in[9];
  const float* ahW  = (const float*)d_in[10];
  const float* ahb  = (const float*)d_in[11];
  const float* acw  = (const float*)d_in[12];
  const float* awW  = (const float*)d_in[13];
  const float* acvW = (const float*)d_in[14];
  const float* acvb = (const float*)d_in[15];
  const float* ecw  = (const float*)d_in[16];
  const float* ecb  = (const float*)d_in[17];
  const float* sW   = (const float*)d_in[18];
  const float* sb   = (const float*)d_in[19];
  const float* ewW  = (const float*)d_in[20];
  const float* ewb  = (const float*)d_in[21];
  const float* cxW  = (const float*)d_in[22];
  const float* cxb  = (const float*)d_in[23];
  const float* cW   = (const float*)d_in[24];
  const float* cb   = (const float*)d_in[25];
  const float* oW   = (const float*)d_in[26];
  const float* ob   = (const float*)d_in[27];
  const int*   lab  = (const int*)d_in[28];
  float* out = (float*)d_out;
  float* ws = (float*)d_ws;

  float* dmask  = ws + 0;        // 8192
  float* ys     = ws + 8192;     // 8192
  float* xs     = ws + 16384;    // 8192
  float* idt    = ws + 24576;    // 128
  float* msum   = ws + 24704;    // 16
  float* avg    = ws + 24720;    // 5472
  float* cctx   = ws + 30192;    // 2048
  float* hbuf   = ws + 32240;    // 4096 (2 x 8 x 256)
  float* qbuf   = ws + 36336;    // 8192 (2 x 8 x 512)
  float* asum   = ws + 44528;    // 8192
  float* energy = ws + 52720;    // 8192
  float* gi     = ws + 60912;    // 221184
  float* embw   = ws + 282096;   // 73728
  float* Mt     = ws + 355824;   // 61952
  float* SO     = ws + 417776;   // 28416
  float* CB     = ws + 446192;   // 896
  float* embwO  = ws + 447088;   // 32000
  float* CO     = ws + 479088;   // 87552
  float* whhT   = ws + 566640;   // 196608
  float* ahWT   = ws + 763248;   // 131072
  float* trans  = ws + 894320;   // 4194304
  float* PO     = ws + 5088624;  // 4194304   (total ~37.1 MB)

  k_p0<<<1, 256, 0, stream>>>(im, dmask, msum, ys, xs, idt, asum);
  k_avg<<<456, 256, 0, stream>>>(cnn, dmask, msum, avg);
  k_init<<<256, 256, 0, stream>>>(avg, iW, ib, cp, cW, cb, hbuf + 2048, cctx);
  k_pre<<<1024, 256, 0, stream>>>(lab, emb, wih, bih, ewW, ewb, gi, embw);
  k_trans<<<dim3(128, 8), 256, 0, stream>>>(cnn, ecw, ecb, ys, xs, idt, trans);
  k_mt<<<121, 256, 0, stream>>>(awW, acw, Mt);
  k_so<<<NV, 256, 0, stream>>>(sW, oW, sb, cxb, cctx, ob, SO, CB);
  k_embwO<<<NV, 512, 0, stream>>>(embw, oW, embwO);
  k_co<<<dim3(3, NV), 256, 0, stream>>>(cxW, oW, CO);
  k_gemm_PO<<<dim3(16, 2, 8), 256, 0, stream>>>(cnn, CO, PO);
  k_tr<<<128, 256, 0, stream>>>(whh, ahW, whhT, ahWT);
  k_gq0<<<dim3(4, 8), 512, 0, stream>>>(hbuf + 2048, whh, bhh, gi, hbuf);
  k_query0<<<64, 512, 0, stream>>>(hbuf, ahW, ahb, qbuf);

  for (int t = 0; t < NT; t++){
    k_eg<<<264, 512, 0, stream>>>(asum, Mt, trans, qbuf, acvW, acvb, gi, whhT, bhh,
                                  ahWT, ahb, hbuf, energy, t);
    k_sap<<<dim3(4, 8), 512, 0, stream>>>(energy, dmask, PO, SO, CB, embwO, hbuf, asum, out, t);
  }
}